// Round 11
// baseline (16488.170 us; speedup 1.0000x reference)
//
#include <hip/hip_runtime.h>
#include <math.h>

#define Bn 512
#define Tn 256
#define Hn 512
#define Vn 7
#define BH (Bn*Hn)          // 262144
#define NLP (Bn*Tn*Vn)      // 917504

#define NBLK 256
#define NTHR 256            // 4 waves; 2 K-halves x 128 threads
#define NGRP 16
#define GBLK 16
#define CNT_STRIDE 32

// ARITHMETIC FROZEN to round-5 (verified): per-half k ascending in quads
// .x.y.z.w, half-combine acc_h0+acc_h1, verbatim epilogue/logit/softmax
// expression trees, libm expf/tanhf/logf. Thread tile 4b x 8r (32 acc) —
// partition change only; every accumulator's FMA sequence is identical.
// LAUNCH ENVELOPE FROZEN to round-9: static __shared__ <= 64 KB, plain
// cooperative launch (round-10 lesson: cooperative + large dynamic LDS
// failed silently -> empty output).

__device__ __forceinline__ float sigf(float x){ return 1.0f/(1.0f + expf(-x)); }

__device__ __forceinline__ void group_barrier(int* cnt, int target){
    __syncthreads();
    if (threadIdx.x == 0){
        __hip_atomic_fetch_add(cnt, 1, __ATOMIC_RELEASE, __HIP_MEMORY_SCOPE_AGENT);
        while (__hip_atomic_load(cnt, __ATOMIC_RELAXED, __HIP_MEMORY_SCOPE_AGENT) < target)
            __builtin_amdgcn_s_sleep(1);
        (void)__hip_atomic_load(cnt, __ATOMIC_ACQUIRE, __HIP_MEMORY_SCOPE_AGENT);
    }
    __syncthreads();
}

__global__ void init_kernel(float* lp, int* cnts){
    int i = blockIdx.x*blockDim.x + threadIdx.x;
    if (i < NGRP) cnts[i*CNT_STRIDE] = 0;
    for (int x = i; x < NLP; x += (int)(gridDim.x*blockDim.x)) lp[x] = 0.0f;
}

// grid 256 x 256. block tile: 32 b x 32 j x 4 gates. 2 K-halves x 128 thr.
// thread tile 4b x 8r; 32-wide k chunks, reg-prefetch -> LDS -> compute.
__global__ void __launch_bounds__(NTHR, 1)
decoder_rnn_kernel(const float* __restrict__ h0, const float* __restrict__ c0,
                   const float* __restrict__ tgt, const float* __restrict__ Wih,
                   const float* __restrict__ Whh, const float* __restrict__ bih,
                   const float* __restrict__ bhh, const float* __restrict__ Wout,
                   const float* __restrict__ bout, float* out, float* ws)
{
    __shared__ float W_lds[2][128*36];   // [hf][r*36+k]
    __shared__ float A_lds[2][32*36];
    __shared__ float hn_lds[32*33];
    __shared__ int   idx_lds[32];

    float* hbuf = ws;                  // 2*BH ping-pong h
    float* cws  = ws + 2*BH;           // BH c-state
    int*   cnts = (int*)(ws + 3*BH);
    float* lp   = out;

    const int bt = blockIdx.x & 15;    // group on one XCD
    const int jt = blockIdx.x >> 4;
    const int b0 = bt << 5;
    const int j0 = jt << 5;
    const int tid  = threadIdx.x;
    const int hf   = tid >> 7;         // K-half 0/1
    const int htid = tid & 127;
    const int tb   = htid & 7;         // b_local = tb + 8*bi
    const int tg   = htid >> 3;        // j-pair: j_local = tg*2 + jj
    int* cnt = cnts + bt*CNT_STRIDE;

    const int gtid = blockIdx.x*NTHR + tid;
    const int nthr = NBLK*NTHR;        // 65536

    // ---- per-block state init (same values as round 5/9) ----
    #pragma unroll
    for (int i = 0; i < 16; ++i){
        const int f = tid + (i << 8);             // 0..4095 = 32 rows x 128 f4
        const int r = f >> 7, c4 = f & 127;
        *(float4*)(hbuf + (long)(b0 + r)*Hn + (c4 << 2)) =
            *(const float4*)(h0 + (long)(b0 + r)*Hn + (c4 << 2));
    }
    {
        const int r = tid >> 3, c4 = tid & 7;     // 32 rows x 8 f4
        *(float4*)(cws + (long)(b0 + r)*Hn + j0 + (c4 << 2)) =
            *(const float4*)(c0 + (long)(b0 + r)*Hn + j0 + (c4 << 2));
    }
    __syncthreads();

    // per-thread LDS read offsets
    int aoff[4], woff[8];
    #pragma unroll
    for (int bi = 0; bi < 4; ++bi) aoff[bi] = (tb + 8*bi)*36;
    #pragma unroll
    for (int gi = 0; gi < 4; ++gi)
        #pragma unroll
        for (int jj = 0; jj < 2; ++jj)
            woff[gi*2 + jj] = ((gi<<5) + (tg<<1) + jj)*36;

    for (int t = 0; t < Tn; ++t){
        const float* hprev = hbuf + (t & 1)*BH;
        float*       hnext = hbuf + ((t + 1) & 1)*BH;

        // ---- argmax (frozen) ----
        if (tid < 32){
            const int  bl = tid;
            const long b  = b0 + bl;
            float best; int am = 0;
            if (t == 0){
                const float* xp = tgt + (b*Tn)*Vn;
                best = xp[0];
                #pragma unroll
                for (int v = 1; v < Vn; ++v){ float xv = xp[v]; if (xv > best){ best = xv; am = v; } }
            } else {
                const float* xp = lp + (b*Tn + (t-1))*Vn;
                best = xp[0] + bout[0];
                #pragma unroll
                for (int v = 1; v < Vn; ++v){ float xv = xp[v] + bout[v]; if (xv > best){ best = xv; am = v; } }
            }
            idx_lds[bl] = am;
        }

        float acc[4][8];   // [bi][gi*2+jj]
        #pragma unroll
        for (int a = 0; a < 4; ++a)
            #pragma unroll
            for (int g = 0; g < 8; ++g) acc[a][g] = 0.0f;

        // ---- prefetch chunk 0: W 8 f4 + A 2 f4 per thread ----
        float4 wreg[8], areg[2];
        {
            const int k0 = hf << 8;
            #pragma unroll
            for (int i = 0; i < 8; ++i){
                const int f = htid + (i << 7);        // 0..1023
                const int r = f >> 3, c4 = f & 7;     // r 0..127
                wreg[i] = *(const float4*)(Whh + (long)(((r>>5)<<9) + j0 + (r&31))*Hn + k0 + (c4 << 2));
            }
            #pragma unroll
            for (int i = 0; i < 2; ++i){
                const int f = htid + (i << 7);        // 0..255
                const int r = f >> 3, c4 = f & 7;     // r 0..31
                areg[i] = *(const float4*)(hprev + (long)(b0 + r)*Hn + k0 + (c4 << 2));
            }
        }

        for (int c = 0; c < 8; ++c){
            __syncthreads();   // prev chunk's LDS reads done (idxl visible at c==0)
            #pragma unroll
            for (int i = 0; i < 8; ++i){
                const int f = htid + (i << 7);
                const int r = f >> 3, c4 = f & 7;
                *(float4*)(&W_lds[hf][r*36 + (c4 << 2)]) = wreg[i];
            }
            #pragma unroll
            for (int i = 0; i < 2; ++i){
                const int f = htid + (i << 7);
                const int r = f >> 3, c4 = f & 7;
                *(float4*)(&A_lds[hf][r*36 + (c4 << 2)]) = areg[i];
            }
            __syncthreads();   // staging visible
            if (c < 7){        // prefetch next chunk during compute
                const int k0 = (hf << 8) + ((c + 1) << 5);
                #pragma unroll
                for (int i = 0; i < 8; ++i){
                    const int f = htid + (i << 7);
                    const int r = f >> 3, c4 = f & 7;
                    wreg[i] = *(const float4*)(Whh + (long)(((r>>5)<<9) + j0 + (r&31))*Hn + k0 + (c4 << 2));
                }
                #pragma unroll
                for (int i = 0; i < 2; ++i){
                    const int f = htid + (i << 7);
                    const int r = f >> 3, c4 = f & 7;
                    areg[i] = *(const float4*)(hprev + (long)(b0 + r)*Hn + k0 + (c4 << 2));
                }
            }
            // ---- compute: 8 k-quads, frozen per-acc order ----
            #pragma unroll 2
            for (int q = 0; q < 8; ++q){
                const int k = q << 2;
                float4 av[4], wv[8];
                #pragma unroll
                for (int i = 0; i < 4; ++i)
                    av[i] = *(const float4*)(&A_lds[hf][aoff[i] + k]);
                #pragma unroll
                for (int i = 0; i < 8; ++i)
                    wv[i] = *(const float4*)(&W_lds[hf][woff[i] + k]);
                #pragma unroll
                for (int bi = 0; bi < 4; ++bi)
                    #pragma unroll
                    for (int g = 0; g < 8; ++g){
                        float s = acc[bi][g];
                        s = fmaf(av[bi].x, wv[g].x, s);
                        s = fmaf(av[bi].y, wv[g].y, s);
                        s = fmaf(av[bi].z, wv[g].z, s);
                        s = fmaf(av[bi].w, wv[g].w, s);
                        acc[bi][g] = s;
                    }
            }
        }

        // ---- half-combine via LDS (frozen: g4 = acc_h0 + acc_h1) ----
        float* red = &W_lds[0][0];     // 128*36 = 4608 floats, exact fit
        __syncthreads();               // GEMM LDS reads done before aliasing
        if (hf == 1){
            #pragma unroll
            for (int bi = 0; bi < 4; ++bi)
                #pragma unroll
                for (int jj = 0; jj < 2; ++jj)
                    *(float4*)(&red[htid*36 + (bi*2 + jj)*4]) =
                        make_float4(acc[bi][0*2+jj], acc[bi][1*2+jj],
                                    acc[bi][2*2+jj], acc[bi][3*2+jj]);
        }
        __syncthreads();

        // ---- epilogue (frozen expressions) ----
        if (hf == 0){
            #pragma unroll
            for (int bi = 0; bi < 4; ++bi){
                const int bl = tb + 8*bi;
                const long b = b0 + bl;
                const int ix = idx_lds[bl];
                float hv2[2], cv2[2];
                #pragma unroll
                for (int jj = 0; jj < 2; ++jj){
                    float4 r4 = *(const float4*)(&red[htid*36 + (bi*2 + jj)*4]);
                    const int j = j0 + (tg<<1) + jj;
                    float g4[4] = { acc[bi][0*2+jj] + r4.x, acc[bi][1*2+jj] + r4.y,
                                    acc[bi][2*2+jj] + r4.z, acc[bi][3*2+jj] + r4.w };
                    #pragma unroll
                    for (int gi = 0; gi < 4; ++gi){
                        const int r = (gi<<9) + j;
                        g4[gi] += Wih[r*Vn + ix] + bih[r] + bhh[r];
                    }
                    const float iv = sigf(g4[0]);
                    const float fv = sigf(g4[1]);
                    const float gv = tanhf(g4[2]);
                    const float ov = sigf(g4[3]);
                    const float cold = cws[b*Hn + j];
                    const float cn = fv*cold + iv*gv;
                    cv2[jj] = cn;
                    const float hn = ov * tanhf(cn);
                    hv2[jj] = hn;
                    hn_lds[bl*33 + (tg<<1) + jj] = hn;
                }
                const int jc = j0 + (tg<<1);
                *(float2*)(&cws[b*Hn + jc])   = make_float2(cv2[0], cv2[1]);
                *(float2*)(&hnext[b*Hn + jc]) = make_float2(hv2[0], hv2[1]);
            }
        }
        __syncthreads();

        // ---- partial logits (frozen) ----
        if (tid < 224){
            const int bl = tid / 7;
            const int v  = tid % 7;
            const float* wo = Wout + v*Hn + j0;
            float s = 0.0f;
            #pragma unroll
            for (int jj = 0; jj < 32; ++jj)
                s = fmaf(hn_lds[bl*33 + jj], wo[jj], s);
            atomicAdd(&lp[((long)(b0 + bl)*Tn + t)*Vn + v], s);
        }

        group_barrier(cnt, GBLK*(t+1));
    }

    // ---- final: hT, cT, log_softmax (frozen exprs) ----
    for (int i = gtid; i < BH; i += nthr){
        out[NLP + i]      = hbuf[i];   // T even -> final h in buffer 0
        out[NLP + BH + i] = cws[i];
    }
    for (long row = gtid; row < (long)Bn*Tn; row += nthr){
        float x[Vn]; float m = -INFINITY;
        #pragma unroll
        for (int v = 0; v < Vn; ++v){ x[v] = lp[row*Vn + v] + bout[v]; m = fmaxf(m, x[v]); }
        float s = 0.0f;
        #pragma unroll
        for (int v = 0; v < Vn; ++v) s += expf(x[v] - m);
        const float ls = logf(s);
        #pragma unroll
        for (int v = 0; v < Vn; ++v) lp[row*Vn + v] = x[v] - m - ls;
    }
}

extern "C" void kernel_launch(void* const* d_in, const int* in_sizes, int n_in,
                              void* d_out, int out_size, void* d_ws, size_t ws_size,
                              hipStream_t stream) {
    const float* h0   = (const float*)d_in[0];
    const float* c0   = (const float*)d_in[1];
    const float* tgt  = (const float*)d_in[2];
    const float* Wih  = (const float*)d_in[3];
    const float* Whh  = (const float*)d_in[4];
    const float* bih  = (const float*)d_in[5];
    const float* bhh  = (const float*)d_in[6];
    const float* Wout = (const float*)d_in[7];
    const float* bout = (const float*)d_in[8];
    float* out = (float*)d_out;
    float* ws  = (float*)d_ws;
    int*   cnts = (int*)(ws + 3*BH);

    init_kernel<<<256, 256, 0, stream>>>(out, cnts);

    void* args[] = { &h0, &c0, &tgt, &Wih, &Whh, &bih, &bhh, &Wout, &bout, &out, &ws };
    (void)hipLaunchCooperativeKernel((const void*)decoder_rnn_kernel,
                               dim3(NBLK), dim3(NTHR), args, 0, stream);
}

// Round 13
// 16468.549 us; speedup vs baseline: 1.0012x; 1.0012x over previous
//
#include <hip/hip_runtime.h>
#include <math.h>

#define Bn 512
#define Tn 256
#define Hn 512
#define Vn 7
#define BH (Bn*Hn)          // 262144
#define NLP (Bn*Tn*Vn)      // 917504

#define NBLK 512            // 32 bt-groups x 16 jt
#define NTHR 256            // 2 K-halves x 128 threads
#define NGRP 32
#define GBLK 16
#define CNT_STRIDE 32

// ARITHMETIC FROZEN to round-5/9 (verified): per-half k ascending in quads
// .x.y.z.w, half-combine acc_h0+acc_h1 via LDS, verbatim epilogue/logit/
// softmax expression trees, libm expf/tanhf/logf.
// LAUNCH: PLAIN <<<>>> launch (round-12 lesson: hipLaunchCooperativeKernel
// silently rejects >256-block grids on this stack; we only need co-residency
// for our own group barriers, not the cooperative API). Groups are contiguous
// 16-block spans -> independent, deadlock-free even under partial residency.
// FINAL OUTPUT IS GROUP-LOCAL (fixes rounds-9/11 latent cross-group race).

__device__ __forceinline__ float sigf(float x){ return 1.0f/(1.0f + expf(-x)); }

__device__ __forceinline__ void group_barrier(int* cnt, int target){
    __syncthreads();
    if (threadIdx.x == 0){
        __hip_atomic_fetch_add(cnt, 1, __ATOMIC_RELEASE, __HIP_MEMORY_SCOPE_AGENT);
        while (__hip_atomic_load(cnt, __ATOMIC_RELAXED, __HIP_MEMORY_SCOPE_AGENT) < target)
            __builtin_amdgcn_s_sleep(1);
        (void)__hip_atomic_load(cnt, __ATOMIC_ACQUIRE, __HIP_MEMORY_SCOPE_AGENT);
    }
    __syncthreads();
}

__global__ void init_kernel(float* lp, int* cnts){
    int i = blockIdx.x*blockDim.x + threadIdx.x;
    if (i < NGRP) cnts[i*CNT_STRIDE] = 0;
    for (int x = i; x < NLP; x += (int)(gridDim.x*blockDim.x)) lp[x] = 0.0f;
}

// grid 512 x 256. block tile: 16 b x 32 j x 4 gates. 2 K-halves x 128 thr.
// thread tile 4b x 4r (16 acc) — round-9 inner loop verbatim.
__global__ void __launch_bounds__(NTHR, 2)
decoder_rnn_kernel(const float* __restrict__ h0, const float* __restrict__ c0,
                   const float* __restrict__ tgt, const float* __restrict__ Wih,
                   const float* __restrict__ Whh, const float* __restrict__ bih,
                   const float* __restrict__ bhh, const float* __restrict__ Wout,
                   const float* __restrict__ bout, float* out, float* ws)
{
    __shared__ float W_lds[2][128*36];   // 36 KB
    __shared__ float A_lds[2][16*36];    // 4.6 KB
    __shared__ float hn_lds[16*33];
    __shared__ int   idx_lds[16];

    float* hbuf = ws;                  // 2*BH ping-pong h
    float* cws  = ws + 2*BH;           // BH c-state
    int*   cnts = (int*)(ws + 3*BH);
    float* lp   = out;

    const int bt = blockIdx.x >> 4;    // 0..31 (group; contiguous 16 blocks)
    const int jt = blockIdx.x & 15;    // 0..15
    const int b0 = bt << 4;            // 16 b rows
    const int j0 = jt << 5;            // 32 j cols
    const int tid  = threadIdx.x;
    const int hf   = tid >> 7;         // K-half 0/1
    const int htid = tid & 127;
    const int tb   = htid & 3;         // b_local = tb + 4*bi
    const int tn   = htid >> 2;        // j 0..31
    int* cnt = cnts + bt*CNT_STRIDE;

    // ---- per-block state init (same values as round 9) ----
    #pragma unroll
    for (int i = 0; i < 8; ++i){
        const int f = tid + (i << 8);             // 0..2047 = 16 rows x 128 f4
        const int r = f >> 7, c4 = f & 127;
        *(float4*)(hbuf + (long)(b0 + r)*Hn + (c4 << 2)) =
            *(const float4*)(h0 + (long)(b0 + r)*Hn + (c4 << 2));
    }
    if (tid < 128){
        const int r = tid >> 3, c4 = tid & 7;     // 16 rows x 8 f4
        *(float4*)(cws + (long)(b0 + r)*Hn + j0 + (c4 << 2)) =
            *(const float4*)(c0 + (long)(b0 + r)*Hn + j0 + (c4 << 2));
    }
    __syncthreads();

    int aoff[4], woff[4];
    #pragma unroll
    for (int bi = 0; bi < 4; ++bi) aoff[bi] = (tb + 4*bi)*36;
    #pragma unroll
    for (int gi = 0; gi < 4; ++gi) woff[gi] = ((gi<<5) + tn)*36;

    for (int t = 0; t < Tn; ++t){
        const float* hprev = hbuf + (t & 1)*BH;
        float*       hnext = hbuf + ((t + 1) & 1)*BH;

        // ---- argmax (frozen) ----
        if (tid < 16){
            const int  bl = tid;
            const long b  = b0 + bl;
            float best; int am = 0;
            if (t == 0){
                const float* xp = tgt + (b*Tn)*Vn;
                best = xp[0];
                #pragma unroll
                for (int v = 1; v < Vn; ++v){ float xv = xp[v]; if (xv > best){ best = xv; am = v; } }
            } else {
                const float* xp = lp + (b*Tn + (t-1))*Vn;
                best = xp[0] + bout[0];
                #pragma unroll
                for (int v = 1; v < Vn; ++v){ float xv = xp[v] + bout[v]; if (xv > best){ best = xv; am = v; } }
            }
            idx_lds[bl] = am;
        }

        float acc[4][4];
        #pragma unroll
        for (int a = 0; a < 4; ++a)
            #pragma unroll
            for (int g = 0; g < 4; ++g) acc[a][g] = 0.0f;

        // ---- prefetch chunk 0: W 8 f4 + A 1 f4 per thread ----
        float4 wreg[8], areg;
        {
            const int k0 = hf << 8;
            #pragma unroll
            for (int i = 0; i < 8; ++i){
                const int f = htid + (i << 7);        // 0..1023
                const int r = f >> 3, c4 = f & 7;     // r 0..127
                wreg[i] = *(const float4*)(Whh + (long)(((r>>5)<<9) + j0 + (r&31))*Hn + k0 + (c4 << 2));
            }
            areg = *(const float4*)(hprev + (long)(b0 + (htid >> 3))*Hn + k0 + ((htid & 7) << 2));
        }

        for (int c = 0; c < 8; ++c){
            __syncthreads();
            #pragma unroll
            for (int i = 0; i < 8; ++i){
                const int f = htid + (i << 7);
                const int r = f >> 3, c4 = f & 7;
                *(float4*)(&W_lds[hf][r*36 + (c4 << 2)]) = wreg[i];
            }
            *(float4*)(&A_lds[hf][(htid >> 3)*36 + ((htid & 7) << 2)]) = areg;
            __syncthreads();
            if (c < 7){   // prefetch next chunk (k0 includes hf<<8 — round-7 lesson)
                const int k0 = (hf << 8) + ((c + 1) << 5);
                #pragma unroll
                for (int i = 0; i < 8; ++i){
                    const int f = htid + (i << 7);
                    const int r = f >> 3, c4 = f & 7;
                    wreg[i] = *(const float4*)(Whh + (long)(((r>>5)<<9) + j0 + (r&31))*Hn + k0 + (c4 << 2));
                }
                areg = *(const float4*)(hprev + (long)(b0 + (htid >> 3))*Hn + k0 + ((htid & 7) << 2));
            }
            // ---- compute chunk c (frozen order, round-9 text) ----
            #pragma unroll 2
            for (int k = 0; k < 32; k += 4){
                float4 av[4], wv[4];
                #pragma unroll
                for (int i = 0; i < 4; ++i)
                    av[i] = *(const float4*)(&A_lds[hf][aoff[i] + k]);
                #pragma unroll
                for (int i = 0; i < 4; ++i)
                    wv[i] = *(const float4*)(&W_lds[hf][woff[i] + k]);
                #pragma unroll
                for (int bi = 0; bi < 4; ++bi)
                    #pragma unroll
                    for (int gi = 0; gi < 4; ++gi){
                        float s = acc[bi][gi];
                        s = fmaf(av[bi].x, wv[gi].x, s);
                        s = fmaf(av[bi].y, wv[gi].y, s);
                        s = fmaf(av[bi].z, wv[gi].z, s);
                        s = fmaf(av[bi].w, wv[gi].w, s);
                        acc[bi][gi] = s;
                    }
            }
        }

        // ---- half-combine via LDS (frozen) ----
        float* red = &W_lds[0][0];     // 128*20 = 2560 floats, fits
        __syncthreads();
        if (hf == 1){
            #pragma unroll
            for (int bi = 0; bi < 4; ++bi)
                *(float4*)(&red[htid*20 + bi*4]) =
                    make_float4(acc[bi][0], acc[bi][1], acc[bi][2], acc[bi][3]);
        }
        __syncthreads();

        // ---- epilogue (frozen expressions) ----
        if (hf == 0){
            #pragma unroll
            for (int bi = 0; bi < 4; ++bi){
                float4 r4 = *(const float4*)(&red[htid*20 + bi*4]);
                const int bl = tb + 4*bi;
                const long b = b0 + bl;
                const int j  = j0 + tn;
                const int ix = idx_lds[bl];
                float g4[4] = { acc[bi][0] + r4.x, acc[bi][1] + r4.y,
                                acc[bi][2] + r4.z, acc[bi][3] + r4.w };
                #pragma unroll
                for (int gi = 0; gi < 4; ++gi){
                    const int r = (gi<<9) + j;
                    g4[gi] += Wih[r*Vn + ix] + bih[r] + bhh[r];
                }
                const float iv = sigf(g4[0]);
                const float fv = sigf(g4[1]);
                const float gv = tanhf(g4[2]);
                const float ov = sigf(g4[3]);
                const float cold = cws[b*Hn + j];
                const float cn = fv*cold + iv*gv;
                cws[b*Hn + j] = cn;
                const float hn = ov * tanhf(cn);
                hnext[b*Hn + j] = hn;
                hn_lds[bl*33 + tn] = hn;
            }
        }
        __syncthreads();

        // ---- partial logits (frozen): 16 b x 7 v threads ----
        if (tid < 112){
            const int bl = tid / 7;
            const int v  = tid % 7;
            const float* wo = Wout + v*Hn + j0;
            float s = 0.0f;
            #pragma unroll
            for (int jj = 0; jj < 32; ++jj)
                s = fmaf(hn_lds[bl*33 + jj], wo[jj], s);
            atomicAdd(&lp[((long)(b0 + bl)*Tn + t)*Vn + v], s);
        }

        group_barrier(cnt, GBLK*(t+1));
    }

    // ---- final: GROUP-LOCAL hT/cT + log_softmax (after group's last barrier;
    // all 16 group blocks have finished -> group rows are final) ----
    {
        const int li = (jt << 9) + (tid << 1);      // 16 blk x 512 = 8192 floats
        const int r = li >> 9, cc = li & 511;       // r 0..15
        *(float2*)(out + NLP + (long)(b0 + r)*Hn + cc) =
            *(const float2*)(hbuf + (long)(b0 + r)*Hn + cc);   // T even -> buf 0
        *(float2*)(out + NLP + BH + (long)(b0 + r)*Hn + cc) =
            *(const float2*)(cws + (long)(b0 + r)*Hn + cc);
    }
    {
        const int  rl  = (jt << 8) + tid;           // 16 blk x 256 = 4096 rows
        const long row = (long)(b0 + (rl >> 8))*Tn + (rl & 255);
        float x[Vn]; float m = -INFINITY;
        #pragma unroll
        for (int v = 0; v < Vn; ++v){ x[v] = lp[row*Vn + v] + bout[v]; m = fmaxf(m, x[v]); }
        float s = 0.0f;
        #pragma unroll
        for (int v = 0; v < Vn; ++v) s += expf(x[v] - m);
        const float ls = logf(s);
        #pragma unroll
        for (int v = 0; v < Vn; ++v) lp[row*Vn + v] = x[v] - m - ls;
    }
}

extern "C" void kernel_launch(void* const* d_in, const int* in_sizes, int n_in,
                              void* d_out, int out_size, void* d_ws, size_t ws_size,
                              hipStream_t stream) {
    const float* h0   = (const float*)d_in[0];
    const float* c0   = (const float*)d_in[1];
    const float* tgt  = (const float*)d_in[2];
    const float* Wih  = (const float*)d_in[3];
    const float* Whh  = (const float*)d_in[4];
    const float* bih  = (const float*)d_in[5];
    const float* bhh  = (const float*)d_in[6];
    const float* Wout = (const float*)d_in[7];
    const float* bout = (const float*)d_in[8];
    float* out = (float*)d_out;
    float* ws  = (float*)d_ws;
    int*   cnts = (int*)(ws + 3*BH);

    init_kernel<<<256, 256, 0, stream>>>(out, cnts);

    decoder_rnn_kernel<<<dim3(NBLK), dim3(NTHR), 0, stream>>>(
        h0, c0, tgt, Wih, Whh, bih, bhh, Wout, bout, out, ws);
}

// Round 14
// 16062.956 us; speedup vs baseline: 1.0265x; 1.0253x over previous
//
#include <hip/hip_runtime.h>
#include <math.h>

#define Bn 512
#define Tn 256
#define Hn 512
#define Vn 7
#define BH (Bn*Hn)          // 262144
#define NLP (Bn*Tn*Vn)      // 917504

#define NBLK 512            // 32 bt-groups x 16 jt
#define NTHR 256            // 2 K-halves x 128 threads
#define NGRP 32
#define GBLK 16
#define CNT_STRIDE 32

// ARITHMETIC FROZEN to round-5/9 (verified): per-half k ascending in quads
// .x.y.z.w, half-combine acc_h0+acc_h1 via LDS, verbatim epilogue/logit/
// softmax expression trees, libm expf/tanhf/logf.
// LAUNCH: plain <<<>>> (cooperative API rejects >256 blocks here).
// BLOCK MAPPING (round-13 lesson: contiguous groups spanned all 8 XCDs ->
// barrier/h lines ping-ponged through HBM, WRITE_SIZE 30 GB):
//   jt = bits[7:4],  bt = bits[2:0]*4 + bit8*2 + bit3
//   -> group members share blockIdx%8 (one XCD: counter + h/lp stay in its L2)
//   -> co-resident CU pair (i, i+256) differ in bit8 -> different groups
//      (one computes while the other spins -> cross-group overlap, m114).

__device__ __forceinline__ float sigf(float x){ return 1.0f/(1.0f + expf(-x)); }

__device__ __forceinline__ void group_barrier(int* cnt, int target){
    __syncthreads();
    if (threadIdx.x == 0){
        __hip_atomic_fetch_add(cnt, 1, __ATOMIC_RELEASE, __HIP_MEMORY_SCOPE_AGENT);
        while (__hip_atomic_load(cnt, __ATOMIC_RELAXED, __HIP_MEMORY_SCOPE_AGENT) < target)
            __builtin_amdgcn_s_sleep(1);
        (void)__hip_atomic_load(cnt, __ATOMIC_ACQUIRE, __HIP_MEMORY_SCOPE_AGENT);
    }
    __syncthreads();
}

__global__ void init_kernel(float* lp, int* cnts){
    int i = blockIdx.x*blockDim.x + threadIdx.x;
    if (i < NGRP) cnts[i*CNT_STRIDE] = 0;
    for (int x = i; x < NLP; x += (int)(gridDim.x*blockDim.x)) lp[x] = 0.0f;
}

// grid 512 x 256. block tile: 16 b x 32 j x 4 gates. 2 K-halves x 128 thr.
// thread tile 4b x 4r (16 acc) — round-9 inner loop verbatim.
__global__ void __launch_bounds__(NTHR, 2)
decoder_rnn_kernel(const float* __restrict__ h0, const float* __restrict__ c0,
                   const float* __restrict__ tgt, const float* __restrict__ Wih,
                   const float* __restrict__ Whh, const float* __restrict__ bih,
                   const float* __restrict__ bhh, const float* __restrict__ Wout,
                   const float* __restrict__ bout, float* out, float* ws)
{
    __shared__ float W_lds[2][128*36];   // 36 KB
    __shared__ float A_lds[2][16*36];    // 4.6 KB
    __shared__ float hn_lds[16*33];
    __shared__ int   idx_lds[16];

    float* hbuf = ws;                  // 2*BH ping-pong h
    float* cws  = ws + 2*BH;           // BH c-state
    int*   cnts = (int*)(ws + 3*BH);
    float* lp   = out;

    // XCD-local group mapping (see header comment)
    const int bix = blockIdx.x;
    const int bt  = ((bix & 7) << 2) | (((bix >> 8) & 1) << 1) | ((bix >> 3) & 1);
    const int jt  = (bix >> 4) & 15;
    const int b0 = bt << 4;            // 16 b rows
    const int j0 = jt << 5;            // 32 j cols
    const int tid  = threadIdx.x;
    const int hf   = tid >> 7;         // K-half 0/1
    const int htid = tid & 127;
    const int tb   = htid & 3;         // b_local = tb + 4*bi
    const int tn   = htid >> 2;        // j 0..31
    int* cnt = cnts + bt*CNT_STRIDE;

    // ---- per-block state init (same values as round 9) ----
    #pragma unroll
    for (int i = 0; i < 8; ++i){
        const int f = tid + (i << 8);             // 0..2047 = 16 rows x 128 f4
        const int r = f >> 7, c4 = f & 127;
        *(float4*)(hbuf + (long)(b0 + r)*Hn + (c4 << 2)) =
            *(const float4*)(h0 + (long)(b0 + r)*Hn + (c4 << 2));
    }
    if (tid < 128){
        const int r = tid >> 3, c4 = tid & 7;     // 16 rows x 8 f4
        *(float4*)(cws + (long)(b0 + r)*Hn + j0 + (c4 << 2)) =
            *(const float4*)(c0 + (long)(b0 + r)*Hn + j0 + (c4 << 2));
    }
    __syncthreads();

    int aoff[4], woff[4];
    #pragma unroll
    for (int bi = 0; bi < 4; ++bi) aoff[bi] = (tb + 4*bi)*36;
    #pragma unroll
    for (int gi = 0; gi < 4; ++gi) woff[gi] = ((gi<<5) + tn)*36;

    for (int t = 0; t < Tn; ++t){
        const float* hprev = hbuf + (t & 1)*BH;
        float*       hnext = hbuf + ((t + 1) & 1)*BH;

        // ---- argmax (frozen) ----
        if (tid < 16){
            const int  bl = tid;
            const long b  = b0 + bl;
            float best; int am = 0;
            if (t == 0){
                const float* xp = tgt + (b*Tn)*Vn;
                best = xp[0];
                #pragma unroll
                for (int v = 1; v < Vn; ++v){ float xv = xp[v]; if (xv > best){ best = xv; am = v; } }
            } else {
                const float* xp = lp + (b*Tn + (t-1))*Vn;
                best = xp[0] + bout[0];
                #pragma unroll
                for (int v = 1; v < Vn; ++v){ float xv = xp[v] + bout[v]; if (xv > best){ best = xv; am = v; } }
            }
            idx_lds[bl] = am;
        }

        float acc[4][4];
        #pragma unroll
        for (int a = 0; a < 4; ++a)
            #pragma unroll
            for (int g = 0; g < 4; ++g) acc[a][g] = 0.0f;

        // ---- prefetch chunk 0: W 8 f4 + A 1 f4 per thread ----
        float4 wreg[8], areg;
        {
            const int k0 = hf << 8;
            #pragma unroll
            for (int i = 0; i < 8; ++i){
                const int f = htid + (i << 7);        // 0..1023
                const int r = f >> 3, c4 = f & 7;     // r 0..127
                wreg[i] = *(const float4*)(Whh + (long)(((r>>5)<<9) + j0 + (r&31))*Hn + k0 + (c4 << 2));
            }
            areg = *(const float4*)(hprev + (long)(b0 + (htid >> 3))*Hn + k0 + ((htid & 7) << 2));
        }

        for (int c = 0; c < 8; ++c){
            __syncthreads();
            #pragma unroll
            for (int i = 0; i < 8; ++i){
                const int f = htid + (i << 7);
                const int r = f >> 3, c4 = f & 7;
                *(float4*)(&W_lds[hf][r*36 + (c4 << 2)]) = wreg[i];
            }
            *(float4*)(&A_lds[hf][(htid >> 3)*36 + ((htid & 7) << 2)]) = areg;
            __syncthreads();
            if (c < 7){   // prefetch next chunk (k0 includes hf<<8 — round-7 lesson)
                const int k0 = (hf << 8) + ((c + 1) << 5);
                #pragma unroll
                for (int i = 0; i < 8; ++i){
                    const int f = htid + (i << 7);
                    const int r = f >> 3, c4 = f & 7;
                    wreg[i] = *(const float4*)(Whh + (long)(((r>>5)<<9) + j0 + (r&31))*Hn + k0 + (c4 << 2));
                }
                areg = *(const float4*)(hprev + (long)(b0 + (htid >> 3))*Hn + k0 + ((htid & 7) << 2));
            }
            // ---- compute chunk c (frozen order, round-9 text) ----
            #pragma unroll 2
            for (int k = 0; k < 32; k += 4){
                float4 av[4], wv[4];
                #pragma unroll
                for (int i = 0; i < 4; ++i)
                    av[i] = *(const float4*)(&A_lds[hf][aoff[i] + k]);
                #pragma unroll
                for (int i = 0; i < 4; ++i)
                    wv[i] = *(const float4*)(&W_lds[hf][woff[i] + k]);
                #pragma unroll
                for (int bi = 0; bi < 4; ++bi)
                    #pragma unroll
                    for (int gi = 0; gi < 4; ++gi){
                        float s = acc[bi][gi];
                        s = fmaf(av[bi].x, wv[gi].x, s);
                        s = fmaf(av[bi].y, wv[gi].y, s);
                        s = fmaf(av[bi].z, wv[gi].z, s);
                        s = fmaf(av[bi].w, wv[gi].w, s);
                        acc[bi][gi] = s;
                    }
            }
        }

        // ---- half-combine via LDS (frozen) ----
        float* red = &W_lds[0][0];     // 128*20 = 2560 floats, fits
        __syncthreads();
        if (hf == 1){
            #pragma unroll
            for (int bi = 0; bi < 4; ++bi)
                *(float4*)(&red[htid*20 + bi*4]) =
                    make_float4(acc[bi][0], acc[bi][1], acc[bi][2], acc[bi][3]);
        }
        __syncthreads();

        // ---- epilogue (frozen expressions) ----
        if (hf == 0){
            #pragma unroll
            for (int bi = 0; bi < 4; ++bi){
                float4 r4 = *(const float4*)(&red[htid*20 + bi*4]);
                const int bl = tb + 4*bi;
                const long b = b0 + bl;
                const int j  = j0 + tn;
                const int ix = idx_lds[bl];
                float g4[4] = { acc[bi][0] + r4.x, acc[bi][1] + r4.y,
                                acc[bi][2] + r4.z, acc[bi][3] + r4.w };
                #pragma unroll
                for (int gi = 0; gi < 4; ++gi){
                    const int r = (gi<<9) + j;
                    g4[gi] += Wih[r*Vn + ix] + bih[r] + bhh[r];
                }
                const float iv = sigf(g4[0]);
                const float fv = sigf(g4[1]);
                const float gv = tanhf(g4[2]);
                const float ov = sigf(g4[3]);
                const float cold = cws[b*Hn + j];
                const float cn = fv*cold + iv*gv;
                cws[b*Hn + j] = cn;
                const float hn = ov * tanhf(cn);
                hnext[b*Hn + j] = hn;
                hn_lds[bl*33 + tn] = hn;
            }
        }
        __syncthreads();

        // ---- partial logits (frozen): 16 b x 7 v threads ----
        if (tid < 112){
            const int bl = tid / 7;
            const int v  = tid % 7;
            const float* wo = Wout + v*Hn + j0;
            float s = 0.0f;
            #pragma unroll
            for (int jj = 0; jj < 32; ++jj)
                s = fmaf(hn_lds[bl*33 + jj], wo[jj], s);
            atomicAdd(&lp[((long)(b0 + bl)*Tn + t)*Vn + v], s);
        }

        group_barrier(cnt, GBLK*(t+1));
    }

    // ---- final: GROUP-LOCAL hT/cT + log_softmax (after group's last barrier;
    // all 16 group blocks have finished -> group rows are final) ----
    {
        const int li = (jt << 9) + (tid << 1);      // 16 blk x 512 = 8192 floats
        const int r = li >> 9, cc = li & 511;       // r 0..15
        *(float2*)(out + NLP + (long)(b0 + r)*Hn + cc) =
            *(const float2*)(hbuf + (long)(b0 + r)*Hn + cc);   // T even -> buf 0
        *(float2*)(out + NLP + BH + (long)(b0 + r)*Hn + cc) =
            *(const float2*)(cws + (long)(b0 + r)*Hn + cc);
    }
    {
        const int  rl  = (jt << 8) + tid;           // 16 blk x 256 = 4096 rows
        const long row = (long)(b0 + (rl >> 8))*Tn + (rl & 255);
        float x[Vn]; float m = -INFINITY;
        #pragma unroll
        for (int v = 0; v < Vn; ++v){ x[v] = lp[row*Vn + v] + bout[v]; m = fmaxf(m, x[v]); }
        float s = 0.0f;
        #pragma unroll
        for (int v = 0; v < Vn; ++v) s += expf(x[v] - m);
        const float ls = logf(s);
        #pragma unroll
        for (int v = 0; v < Vn; ++v) lp[row*Vn + v] = x[v] - m - ls;
    }
}

extern "C" void kernel_launch(void* const* d_in, const int* in_sizes, int n_in,
                              void* d_out, int out_size, void* d_ws, size_t ws_size,
                              hipStream_t stream) {
    const float* h0   = (const float*)d_in[0];
    const float* c0   = (const float*)d_in[1];
    const float* tgt  = (const float*)d_in[2];
    const float* Wih  = (const float*)d_in[3];
    const float* Whh  = (const float*)d_in[4];
    const float* bih  = (const float*)d_in[5];
    const float* bhh  = (const float*)d_in[6];
    const float* Wout = (const float*)d_in[7];
    const float* bout = (const float*)d_in[8];
    float* out = (float*)d_out;
    float* ws  = (float*)d_ws;
    int*   cnts = (int*)(ws + 3*BH);

    init_kernel<<<256, 256, 0, stream>>>(out, cnts);

    decoder_rnn_kernel<<<dim3(NBLK), dim3(NTHR), 0, stream>>>(
        h0, c0, tgt, Wih, Whh, bih, bhh, Wout, bout, out, ws);
}